// Round 1
// baseline (714.827 us; speedup 1.0000x reference)
//
#include <hip/hip_runtime.h>
#include <stdint.h>

#define S_LEN 2048
#define HID   2560
#define NH    32
#define NKV   8
#define DH    128
#define QD    (NH*DH)    // 4096
#define KVD   (NKV*DH)   // 1024

typedef __attribute__((ext_vector_type(8))) short          bf16x8;
typedef __attribute__((ext_vector_type(4))) float          f32x4;
typedef __attribute__((ext_vector_type(8))) unsigned short us8;

static __device__ __forceinline__ unsigned short f2bf(float f) {
  union { float f; uint32_t u; } v; v.f = f;
  uint32_t u = v.u;
  u += 0x7fff + ((u >> 16) & 1);   // RNE
  return (unsigned short)(u >> 16);
}

static __device__ __forceinline__ void gload16(const void* g, void* l) {
  __builtin_amdgcn_global_load_lds(
      (const __attribute__((address_space(1))) uint32_t*)g,
      (__attribute__((address_space(3))) uint32_t*)l, 16, 0, 0);
}

// ---------------------------------------------------------------- cast f32->bf16
__global__ void cast_bf16_k(const float* __restrict__ in,
                            unsigned short* __restrict__ out, int n4) {
  int stride = gridDim.x * blockDim.x;
  for (int i = blockIdx.x * blockDim.x + threadIdx.x; i < n4; i += stride) {
    float4 v = ((const float4*)in)[i];
    ushort4 o;
    o.x = f2bf(v.x); o.y = f2bf(v.y); o.z = f2bf(v.z); o.w = f2bf(v.w);
    ((ushort4*)out)[i] = o;
  }
}

// ---------------------------------------------------------------- GEMM  C = A * B^T
// A: [M][K] bf16 row-major, B: [N][K] bf16 row-major (torch Linear weight)
// OUTBF=0 -> f32 C, OUTBF=1 -> bf16 C.  M,N multiples of 128, K multiple of 32.
#define BM 128
#define BN 128
#define BK 32

template <int OUTBF>
__global__ __launch_bounds__(256)
void gemm_bt(const unsigned short* __restrict__ A,
             const unsigned short* __restrict__ B,
             float* __restrict__ Cf, unsigned short* __restrict__ Cb,
             int M, int N, int K)
{
  __shared__ __align__(16) unsigned short sA[BM * BK];
  __shared__ __align__(16) unsigned short sB[BN * BK];
  const int tid  = threadIdx.x;
  const int wave = tid >> 6, lane = tid & 63;
  const int wr   = wave >> 1, wc = wave & 1;
  const int brow = blockIdx.y, bcol = blockIdx.x;
  const int l15  = lane & 15, lh = lane >> 4;

  f32x4 acc[4][4] = {};

  for (int k0 = 0; k0 < K; k0 += BK) {
    __syncthreads();
#pragma unroll
    for (int c = 0; c < 2; ++c) {
      int chunk = wave * 2 + c;               // 0..7, 1KiB each
      int f = chunk * 512 + lane * 8;         // flat bf16 index in tile
      int row = f >> 5, col = f & 31;
      gload16(A + (size_t)(brow * BM + row) * K + k0 + col, (char*)sA + chunk * 1024);
      gload16(B + (size_t)(bcol * BN + row) * K + k0 + col, (char*)sB + chunk * 1024);
    }
    __syncthreads();

    bf16x8 af[4], bfr[4];
#pragma unroll
    for (int i = 0; i < 4; ++i)
      af[i] = *(const bf16x8*)((const char*)sA + (wr * 64 + i * 16 + l15) * 64 + lh * 16);
#pragma unroll
    for (int j = 0; j < 4; ++j)
      bfr[j] = *(const bf16x8*)((const char*)sB + (wc * 64 + j * 16 + l15) * 64 + lh * 16);
#pragma unroll
    for (int i = 0; i < 4; ++i)
#pragma unroll
      for (int j = 0; j < 4; ++j)
        acc[i][j] = __builtin_amdgcn_mfma_f32_16x16x32_bf16(af[i], bfr[j], acc[i][j], 0, 0, 0);
  }

#pragma unroll
  for (int i = 0; i < 4; ++i)
#pragma unroll
    for (int j = 0; j < 4; ++j) {
      int row = brow * BM + wr * 64 + i * 16 + lh * 4;
      int col = bcol * BN + wc * 64 + j * 16 + l15;
#pragma unroll
      for (int r = 0; r < 4; ++r) {
        if (OUTBF) Cb[(size_t)(row + r) * N + col] = f2bf(acc[i][j][r]);
        else       Cf[(size_t)(row + r) * N + col] = acc[i][j][r];
      }
    }
}

// ---------------------------------------------------------------- RMSNorm + RoPE
// one wave per (s, head) row of 128; heads 0..31 -> Q, 32..39 -> K
__global__ __launch_bounds__(256)
void normrope_k(const float* __restrict__ qf, const float* __restrict__ kf,
                const float* __restrict__ freqs,
                const float* __restrict__ qw, const float* __restrict__ kw,
                unsigned short* __restrict__ qb, unsigned short* __restrict__ kb)
{
  int wid  = blockIdx.x * 4 + (threadIdx.x >> 6);
  int lane = threadIdx.x & 63;
  int s = wid / (NH + NKV);
  int h = wid % (NH + NKV);
  const float* src; unsigned short* dst; const float* w;
  if (h < NH) { src = qf + (size_t)s * QD + h * DH;        dst = qb + (size_t)s * QD + h * DH;        w = qw; }
  else { int hk = h - NH;
         src = kf + (size_t)s * KVD + hk * DH;             dst = kb + (size_t)s * KVD + hk * DH;      w = kw; }
  float x1 = src[lane], x2 = src[lane + 64];
  float ss = x1 * x1 + x2 * x2;
  ss += __shfl_xor(ss, 1);  ss += __shfl_xor(ss, 2);  ss += __shfl_xor(ss, 4);
  ss += __shfl_xor(ss, 8);  ss += __shfl_xor(ss, 16); ss += __shfl_xor(ss, 32);
  float rs = rsqrtf(ss * (1.0f / 128.0f) + 1e-6f);
  float y1 = x1 * rs * w[lane], y2 = x2 * rs * w[lane + 64];
  const float* cosr = freqs + (size_t)s * DH;
  const float* sinr = freqs + (size_t)(S_LEN + s) * DH;
  float o1 = y1 * cosr[lane]      - y2 * sinr[lane];
  float o2 = y2 * cosr[lane + 64] + y1 * sinr[lane + 64];
  dst[lane]      = f2bf(o1);
  dst[lane + 64] = f2bf(o2);
}

// ---------------------------------------------------------------- flash attention
// grid (S/64, H). block 256 = 4 waves; wave owns 16 q-rows. KV tiles of 64.
__global__ __launch_bounds__(256)
void attn_k(const unsigned short* __restrict__ Q,   // [S][4096] bf16 (normed+roped)
            const unsigned short* __restrict__ Kb,  // [S][1024] bf16 (normed+roped)
            const unsigned short* __restrict__ Vb,  // [S][1024] bf16
            unsigned short* __restrict__ O)         // [S][4096] bf16
{
  const float SCALE = 0.08838834764831845f;   // 1/sqrt(128)
  const float L2E   = 1.4426950408889634f;
  __shared__ __align__(16) unsigned short sK[64 * 128];    // XOR-swizzled rows (256B)
  __shared__ __align__(16) unsigned short sV[128][72];     // sV[d][kv], padded
  __shared__ __align__(16) unsigned short sP[4][16 * 72];  // per-wave P tile, padded

  int h = blockIdx.y, kvh = h >> 2;
  int q0 = blockIdx.x * 64;
  int wave = threadIdx.x >> 6, lane = threadIdx.x & 63;
  int l15 = lane & 15, lh = lane >> 4;

  // Q fragments (A-layout): row = l15, k = kk*32 + lh*8 + j
  bf16x8 qf[4];
  {
    const unsigned short* qp = Q + (size_t)(q0 + wave * 16 + l15) * QD + h * DH + lh * 8;
#pragma unroll
    for (int kk = 0; kk < 4; ++kk) qf[kk] = *(const bf16x8*)(qp + kk * 32);
  }

  f32x4 oacc[8] = {};
  float m_r[4], l_r[4];
#pragma unroll
  for (int r = 0; r < 4; ++r) { m_r[r] = -1e30f; l_r[r] = 0.f; }

  int vc0 = (threadIdx.x >> 6) * 32;   // wave -> 32 d-columns
  int vlane = lane;                    // kv row

  for (int t0 = 0; t0 < S_LEN; t0 += 64) {
    __syncthreads();
    // ---- stage K (global_load_lds, pre-swizzled source; involution byte^((row&7)<<4))
#pragma unroll
    for (int c = 0; c < 4; ++c) {
      int chunk = wave * 4 + c;                  // 16 chunks of 1KiB
      int fb = chunk * 1024 + lane * 16;         // dest byte
      int row = fb >> 8;
      int ginner = (fb & 255) ^ ((row & 7) << 4);
      gload16(Kb + (size_t)(t0 + row) * KVD + kvh * DH + (ginner >> 1),
              (char*)sK + chunk * 1024);
    }
    // ---- stage V transposed: lane = kv row, wave = 32-col segment (conflict-free writes)
    {
      const unsigned short* vsrc = Vb + (size_t)(t0 + vlane) * KVD + kvh * DH + vc0;
      us8 vv[4];
#pragma unroll
      for (int u = 0; u < 4; ++u) vv[u] = *(const us8*)(vsrc + u * 8);
#pragma unroll
      for (int u = 0; u < 4; ++u)
#pragma unroll
        for (int k = 0; k < 8; ++k)
          sV[vc0 + u * 8 + k][vlane] = (unsigned short)vv[u][k];
    }
    __syncthreads();

    // ---- QK^T : sacc[t] covers kv cols t*16+l15, rows lh*4+r
    f32x4 sacc[4] = {};
#pragma unroll
    for (int t = 0; t < 4; ++t) {
      int krow = t * 16 + l15;
      int rb = krow * 256;
      int sw = (krow & 7) << 4;
#pragma unroll
      for (int kk = 0; kk < 4; ++kk) {
        bf16x8 kf = *(const bf16x8*)((const char*)sK + rb + (((kk * 64) + lh * 16) ^ sw));
        sacc[t] = __builtin_amdgcn_mfma_f32_16x16x32_bf16(qf[kk], kf, sacc[t], 0, 0, 0);
      }
    }

    // ---- online softmax (rows live on lane&15-replicated groups)
    float corr[4];
#pragma unroll
    for (int r = 0; r < 4; ++r) {
      float v0 = fmaxf(fmaxf(sacc[0][r], sacc[1][r]), fmaxf(sacc[2][r], sacc[3][r]));
      v0 = fmaxf(v0, __shfl_xor(v0, 1));
      v0 = fmaxf(v0, __shfl_xor(v0, 2));
      v0 = fmaxf(v0, __shfl_xor(v0, 4));
      v0 = fmaxf(v0, __shfl_xor(v0, 8));
      float mt = v0 * SCALE;
      float mn = fmaxf(m_r[r], mt);
      corr[r] = exp2f((m_r[r] - mn) * L2E);
      m_r[r] = mn;
    }
#pragma unroll
    for (int r = 0; r < 4; ++r) {
      float p0 = exp2f((sacc[0][r] * SCALE - m_r[r]) * L2E);
      float p1 = exp2f((sacc[1][r] * SCALE - m_r[r]) * L2E);
      float p2 = exp2f((sacc[2][r] * SCALE - m_r[r]) * L2E);
      float p3 = exp2f((sacc[3][r] * SCALE - m_r[r]) * L2E);
      unsigned short* pr = sP[wave] + (lh * 4 + r) * 72;
      pr[0 * 16 + l15] = f2bf(p0);
      pr[1 * 16 + l15] = f2bf(p1);
      pr[2 * 16 + l15] = f2bf(p2);
      pr[3 * 16 + l15] = f2bf(p3);
      float rs_ = p0 + p1 + p2 + p3;
      rs_ += __shfl_xor(rs_, 1); rs_ += __shfl_xor(rs_, 2);
      rs_ += __shfl_xor(rs_, 4); rs_ += __shfl_xor(rs_, 8);
      l_r[r] = l_r[r] * corr[r] + rs_;
    }
#pragma unroll
    for (int ct = 0; ct < 8; ++ct)
#pragma unroll
      for (int r = 0; r < 4; ++r) oacc[ct][r] *= corr[r];

    // ---- PV : A = P (from sP), B = V^T (from sV)
#pragma unroll
    for (int kk = 0; kk < 2; ++kk) {
      bf16x8 pa = *(const bf16x8*)((const char*)sP[wave] + (l15 * 72 + kk * 32 + lh * 8) * 2);
#pragma unroll
      for (int ct = 0; ct < 8; ++ct) {
        bf16x8 vf = *(const bf16x8*)((const char*)sV + ((ct * 16 + l15) * 72 + kk * 32 + lh * 8) * 2);
        oacc[ct] = __builtin_amdgcn_mfma_f32_16x16x32_bf16(pa, vf, oacc[ct], 0, 0, 0);
      }
    }
  }

  // ---- epilogue
#pragma unroll
  for (int r = 0; r < 4; ++r) {
    float inv = 1.0f / l_r[r];
    size_t orow = (size_t)(q0 + wave * 16 + lh * 4 + r) * QD + h * DH;
#pragma unroll
    for (int ct = 0; ct < 8; ++ct)
      O[orow + ct * 16 + l15] = f2bf(oacc[ct][r] * inv);
  }
}

// ---------------------------------------------------------------- launcher
extern "C" void kernel_launch(void* const* d_in, const int* in_sizes, int n_in,
                              void* d_out, int out_size, void* d_ws, size_t ws_size,
                              hipStream_t stream)
{
  const float* hs    = (const float*)d_in[0];
  const float* freqs = (const float*)d_in[1];
  const float* Wq    = (const float*)d_in[2];
  const float* Wk    = (const float*)d_in[3];
  const float* Wv    = (const float*)d_in[4];
  const float* Wo    = (const float*)d_in[5];
  const float* qw    = (const float*)d_in[6];
  const float* kw    = (const float*)d_in[7];
  float* out = (float*)d_out;

  char* ws = (char*)d_ws;
  size_t off = 0;
  auto alloc = [&](size_t bytes) {
    char* p = ws + off;
    off += (bytes + 255) & ~(size_t)255;
    return p;
  };
  unsigned short* hs_b = (unsigned short*)alloc((size_t)S_LEN * HID * 2);
  unsigned short* Wq_b = (unsigned short*)alloc((size_t)QD * HID * 2);
  unsigned short* Wk_b = (unsigned short*)alloc((size_t)KVD * HID * 2);
  unsigned short* Wv_b = (unsigned short*)alloc((size_t)KVD * HID * 2);
  unsigned short* Wo_b = (unsigned short*)alloc((size_t)HID * QD * 2);
  float*          q_f  = (float*)alloc((size_t)S_LEN * QD * 4);
  float*          k_f  = (float*)alloc((size_t)S_LEN * KVD * 4);
  unsigned short* q_b  = (unsigned short*)alloc((size_t)S_LEN * QD * 2);
  unsigned short* k_b  = (unsigned short*)alloc((size_t)S_LEN * KVD * 2);
  unsigned short* v_b  = (unsigned short*)alloc((size_t)S_LEN * KVD * 2);
  unsigned short* at_b = (unsigned short*)q_f;   // q_f dead after normrope; reuse

  auto cast = [&](const float* src, unsigned short* dst, int n) {
    int n4 = n / 4;
    int blocks = (n4 + 255) / 256; if (blocks > 2048) blocks = 2048;
    cast_bf16_k<<<dim3(blocks), dim3(256), 0, stream>>>(src, dst, n4);
  };
  cast(hs, hs_b, S_LEN * HID);
  cast(Wq, Wq_b, QD * HID);
  cast(Wk, Wk_b, KVD * HID);
  cast(Wv, Wv_b, KVD * HID);
  cast(Wo, Wo_b, HID * QD);

  gemm_bt<0><<<dim3(QD / BN, S_LEN / BM), dim3(256), 0, stream>>>(
      hs_b, Wq_b, q_f, (unsigned short*)nullptr, S_LEN, QD, HID);
  gemm_bt<0><<<dim3(KVD / BN, S_LEN / BM), dim3(256), 0, stream>>>(
      hs_b, Wk_b, k_f, (unsigned short*)nullptr, S_LEN, KVD, HID);
  gemm_bt<1><<<dim3(KVD / BN, S_LEN / BM), dim3(256), 0, stream>>>(
      hs_b, Wv_b, (float*)nullptr, v_b, S_LEN, KVD, HID);

  normrope_k<<<dim3(S_LEN * (NH + NKV) / 4), dim3(256), 0, stream>>>(
      q_f, k_f, freqs, qw, kw, q_b, k_b);

  attn_k<<<dim3(S_LEN / 64, NH), dim3(256), 0, stream>>>(q_b, k_b, v_b, at_b);

  gemm_bt<0><<<dim3(HID / BN, S_LEN / BM), dim3(256), 0, stream>>>(
      at_b, Wo_b, out, (unsigned short*)nullptr, S_LEN, HID, QD);
}

// Round 3
// 521.916 us; speedup vs baseline: 1.3696x; 1.3696x over previous
//
#include <hip/hip_runtime.h>
#include <stdint.h>

#define S_LEN 2048
#define HID   2560
#define NH    32
#define NKV   8
#define DH    128
#define QD    (NH*DH)    // 4096
#define KVD   (NKV*DH)   // 1024

typedef __attribute__((ext_vector_type(8))) short          bf16x8;
typedef __attribute__((ext_vector_type(4))) float          f32x4;
typedef __attribute__((ext_vector_type(8))) unsigned short us8;

static __device__ __forceinline__ unsigned short f2bf(float f) {
  union { float f; uint32_t u; } v; v.f = f;
  uint32_t u = v.u;
  u += 0x7fff + ((u >> 16) & 1);   // RNE
  return (unsigned short)(u >> 16);
}

static __device__ __forceinline__ void gload16(const void* g, void* l) {
  __builtin_amdgcn_global_load_lds(
      (const __attribute__((address_space(1))) uint32_t*)g,
      (__attribute__((address_space(3))) uint32_t*)l, 16, 0, 0);
}

static __device__ __forceinline__ unsigned cvtpk(float lo, float hi) {
  unsigned r;
  asm volatile("v_cvt_pk_bf16_f32 %0, %1, %2" : "=v"(r) : "v"(lo), "v"(hi));
  return r;
}

// ---------------------------------------------------------------- cast f32->bf16
__global__ void cast_bf16_k(const float* __restrict__ in,
                            unsigned short* __restrict__ out, int n4) {
  int stride = gridDim.x * blockDim.x;
  for (int i = blockIdx.x * blockDim.x + threadIdx.x; i < n4; i += stride) {
    float4 v = ((const float4*)in)[i];
    ushort4 o;
    o.x = f2bf(v.x); o.y = f2bf(v.y); o.z = f2bf(v.z); o.w = f2bf(v.w);
    ((ushort4*)out)[i] = o;
  }
}

// ---------------------------------------------------------------- GEMM  C = A * B^T (f32 out)
#define BM 128
#define BN 128
#define BK 32

__global__ __launch_bounds__(256)
void gemm_bt(const unsigned short* __restrict__ A,
             const unsigned short* __restrict__ B,
             float* __restrict__ Cf, int M, int N, int K)
{
  __shared__ __align__(16) unsigned short sA[BM * BK];
  __shared__ __align__(16) unsigned short sB[BN * BK];
  const int tid  = threadIdx.x;
  const int wave = tid >> 6, lane = tid & 63;
  const int wr   = wave >> 1, wc = wave & 1;
  const int brow = blockIdx.y, bcol = blockIdx.x;
  const int l15  = lane & 15, lh = lane >> 4;

  f32x4 acc[4][4] = {};

  for (int k0 = 0; k0 < K; k0 += BK) {
    __syncthreads();
#pragma unroll
    for (int c = 0; c < 2; ++c) {
      int chunk = wave * 2 + c;
      int f = chunk * 512 + lane * 8;
      int row = f >> 5, col = f & 31;
      gload16(A + (size_t)(brow * BM + row) * K + k0 + col, (char*)sA + chunk * 1024);
      gload16(B + (size_t)(bcol * BN + row) * K + k0 + col, (char*)sB + chunk * 1024);
    }
    __syncthreads();

    bf16x8 af[4], bfr[4];
#pragma unroll
    for (int i = 0; i < 4; ++i)
      af[i] = *(const bf16x8*)((const char*)sA + (wr * 64 + i * 16 + l15) * 64 + lh * 16);
#pragma unroll
    for (int j = 0; j < 4; ++j)
      bfr[j] = *(const bf16x8*)((const char*)sB + (wc * 64 + j * 16 + l15) * 64 + lh * 16);
#pragma unroll
    for (int i = 0; i < 4; ++i)
#pragma unroll
      for (int j = 0; j < 4; ++j)
        acc[i][j] = __builtin_amdgcn_mfma_f32_16x16x32_bf16(af[i], bfr[j], acc[i][j], 0, 0, 0);
  }

#pragma unroll
  for (int i = 0; i < 4; ++i)
#pragma unroll
    for (int j = 0; j < 4; ++j) {
      int row = brow * BM + wr * 64 + i * 16 + lh * 4;
      int col = bcol * BN + wc * 64 + j * 16 + l15;
#pragma unroll
      for (int r = 0; r < 4; ++r)
        Cf[(size_t)(row + r) * N + col] = acc[i][j][r];
    }
}

// ---------------------------------------------------------------- fused QKV GEMM + RMSNorm + RoPE
__global__ __launch_bounds__(256)
void gemm_qkv(const unsigned short* __restrict__ A,
              const unsigned short* __restrict__ B,
              const float* __restrict__ freqs,
              const float* __restrict__ qw, const float* __restrict__ kw,
              unsigned short* __restrict__ Qo,
              unsigned short* __restrict__ Ko,
              unsigned short* __restrict__ Vo)
{
  __shared__ __align__(16) unsigned short sA[BM * BK];
  __shared__ __align__(16) unsigned short sB[BN * BK];
  const int tid  = threadIdx.x;
  const int wave = tid >> 6, lane = tid & 63;
  const int brow = blockIdx.y, bcol = blockIdx.x;
  const int l15  = lane & 15, lh = lane >> 4;

  f32x4 acc[2][8] = {};

  for (int k0 = 0; k0 < HID; k0 += BK) {
    __syncthreads();
#pragma unroll
    for (int c = 0; c < 2; ++c) {
      int chunk = wave * 2 + c;
      int f = chunk * 512 + lane * 8;
      int row = f >> 5, col = f & 31;
      gload16(A + (size_t)(brow * BM + row) * HID + k0 + col, (char*)sA + chunk * 1024);
      gload16(B + (size_t)(bcol * BN + row) * HID + k0 + col, (char*)sB + chunk * 1024);
    }
    __syncthreads();

    bf16x8 af[2], bfr[8];
#pragma unroll
    for (int i = 0; i < 2; ++i)
      af[i] = *(const bf16x8*)((const char*)sA + (wave * 32 + i * 16 + l15) * 64 + lh * 16);
#pragma unroll
    for (int j = 0; j < 8; ++j)
      bfr[j] = *(const bf16x8*)((const char*)sB + (j * 16 + l15) * 64 + lh * 16);
#pragma unroll
    for (int i = 0; i < 2; ++i)
#pragma unroll
      for (int j = 0; j < 8; ++j)
        acc[i][j] = __builtin_amdgcn_mfma_f32_16x16x32_bf16(af[i], bfr[j], acc[i][j], 0, 0, 0);
  }

  const int ncol0  = bcol * BN;
  const int region = (ncol0 < QD) ? 0 : (ncol0 < QD + KVD ? 1 : 2);
  const float* nw  = (region == 0) ? qw : kw;

#pragma unroll
  for (int i = 0; i < 2; ++i) {
#pragma unroll
    for (int r = 0; r < 4; ++r) {
      int s = brow * BM + wave * 32 + i * 16 + lh * 4 + r;
      float v[8];
#pragma unroll
      for (int j = 0; j < 8; ++j) v[j] = acc[i][j][r];
      if (region < 2) {
        float ss = 0.f;
#pragma unroll
        for (int j = 0; j < 8; ++j) ss += v[j] * v[j];
        ss += __shfl_xor(ss, 1); ss += __shfl_xor(ss, 2);
        ss += __shfl_xor(ss, 4); ss += __shfl_xor(ss, 8);
        float rsq = rsqrtf(ss * (1.0f / 128.0f) + 1e-6f);
        float y[8];
#pragma unroll
        for (int j = 0; j < 8; ++j) y[j] = v[j] * rsq * nw[j * 16 + l15];
        const float* cr = freqs + (size_t)s * DH;
        const float* sr = freqs + (size_t)(S_LEN + s) * DH;
#pragma unroll
        for (int j = 0; j < 4; ++j) {
          int d1 = j * 16 + l15, d2 = (j + 4) * 16 + l15;
          v[j]     = y[j]     * cr[d1] - y[j + 4] * sr[d1];
          v[j + 4] = y[j + 4] * cr[d2] + y[j]     * sr[d2];
        }
      }
      unsigned short* dst;
      if (region == 0)      dst = Qo + (size_t)s * QD  + ncol0;
      else if (region == 1) dst = Ko + (size_t)s * KVD + (ncol0 - QD);
      else                  dst = Vo + (size_t)s * KVD + (ncol0 - QD - KVD);
#pragma unroll
      for (int j = 0; j < 8; ++j) dst[j * 16 + l15] = f2bf(v[j]);
    }
  }
}

// ---------------------------------------------------------------- flash attention (swapped-QK, GQA-shared KV)
// grid (S/32, NKV). block 256 = 4 waves; wave w = head kvh*4+w, 32 q-rows.
// sK: XOR-swizzled row-major [64][128] (round-0-proven).
// sV: padded transpose [d][kv] [128][72] (round-0-proven), reg write-transpose.
__global__ __launch_bounds__(256, 2)
void attn2_k(const unsigned short* __restrict__ Q,
             const unsigned short* __restrict__ Kb,
             const unsigned short* __restrict__ Vb,
             unsigned short* __restrict__ O)
{
  const float SCALE = 0.08838834764831845f;   // 1/sqrt(128)
  const float L2E   = 1.4426950408889634f;
  __shared__ __align__(16) unsigned short sK[2][64 * 128];
  __shared__ __align__(16) unsigned short sV[2][128][72];

  const int kvh  = blockIdx.y;
  const int q0   = blockIdx.x * 32;
  const int wave = threadIdx.x >> 6, lane = threadIdx.x & 63;
  const int l15  = lane & 15, lh = lane >> 4;
  const int h    = kvh * 4 + wave;
  const int vc0  = wave * 32;

  // Q fragments: B-operand layout (n=l15=q-row, k=lh*8+j)
  bf16x8 qf[2][4];
#pragma unroll
  for (int qt = 0; qt < 2; ++qt) {
    const unsigned short* qp = Q + (size_t)(q0 + qt * 16 + l15) * QD + h * DH + lh * 8;
#pragma unroll
    for (int kk = 0; kk < 4; ++kk) qf[qt][kk] = *(const bf16x8*)(qp + kk * 32);
  }

  f32x4 oacc[2][8] = {};
  float m_q[2] = { -1e30f, -1e30f }, l_q[2] = { 0.f, 0.f };

  auto stageK = [&](int b, int t0) {
#pragma unroll
    for (int c = 0; c < 4; ++c) {
      int chunk = wave * 4 + c;
      int fb = chunk * 1024 + lane * 16;
      int row = fb >> 8;
      int gi = (fb & 255) ^ ((row & 7) << 4);
      gload16(Kb + (size_t)(t0 + row) * KVD + kvh * DH + (gi >> 1),
              (char*)sK[b] + chunk * 1024);
    }
  };
  auto loadV = [&](us8* vv, int t0) {
    const unsigned short* vsrc = Vb + (size_t)(t0 + lane) * KVD + kvh * DH + vc0;
#pragma unroll
    for (int u = 0; u < 4; ++u) vv[u] = *(const us8*)(vsrc + u * 8);
  };
  auto writeV = [&](int b, const us8* vv) {
#pragma unroll
    for (int u = 0; u < 4; ++u)
#pragma unroll
      for (int k = 0; k < 8; ++k)
        sV[b][vc0 + u * 8 + k][lane] = (unsigned short)vv[u][k];
  };

  {
    us8 vv[4];
    stageK(0, 0);
    loadV(vv, 0);
    writeV(0, vv);
  }
  asm volatile("s_waitcnt vmcnt(0)" ::: "memory");
  __syncthreads();
  int buf = 0;

  const int srcA = (lh & 1) * 32 + l15;
  const int srcB = srcA + 16;
  const bool thi = (lh >> 1) != 0;

  for (int t = 0; t < S_LEN / 64; ++t) {
    const bool pre = (t + 1 < S_LEN / 64);
    us8 vv[4];
    if (pre) { stageK(buf ^ 1, (t + 1) * 64); loadV(vv, (t + 1) * 64); }

    // ---- QK^T swapped: sacc[qt][tt][r] on lane(lh,l15) = S[k=tt*16+lh*4+r][q=qt*16+l15]
    f32x4 sacc[2][4] = {};
#pragma unroll
    for (int kk = 0; kk < 4; ++kk) {
      bf16x8 kf[4];
#pragma unroll
      for (int tt = 0; tt < 4; ++tt) {
        int krow = tt * 16 + l15;
        kf[tt] = *(const bf16x8*)((const char*)sK[buf] + krow * 256 +
                                  ((kk * 64 + lh * 16) ^ ((krow & 7) << 4)));
      }
#pragma unroll
      for (int tt = 0; tt < 4; ++tt) {
        sacc[0][tt] = __builtin_amdgcn_mfma_f32_16x16x32_bf16(kf[tt], qf[0][kk], sacc[0][tt], 0, 0, 0);
        sacc[1][tt] = __builtin_amdgcn_mfma_f32_16x16x32_bf16(kf[tt], qf[1][kk], sacc[1][tt], 0, 0, 0);
      }
    }

    // ---- online softmax, fully in-register (q-row = l15; reduce over lh)
    unsigned pk[2][4][2];
    float corr[2];
#pragma unroll
    for (int qt = 0; qt < 2; ++qt) {
      float mx = sacc[qt][0][0];
#pragma unroll
      for (int tt = 0; tt < 4; ++tt)
#pragma unroll
        for (int r = 0; r < 4; ++r) mx = fmaxf(mx, sacc[qt][tt][r]);
      mx = fmaxf(mx, __shfl_xor(mx, 16));
      mx = fmaxf(mx, __shfl_xor(mx, 32));
      float mn = fmaxf(m_q[qt], mx * SCALE);
      corr[qt] = exp2f((m_q[qt] - mn) * L2E);
      m_q[qt] = mn;
      float sum = 0.f;
      float p[4][4];
#pragma unroll
      for (int tt = 0; tt < 4; ++tt)
#pragma unroll
        for (int r = 0; r < 4; ++r) {
          p[tt][r] = exp2f((sacc[qt][tt][r] * SCALE - mn) * L2E);
          sum += p[tt][r];
        }
      sum += __shfl_xor(sum, 16);
      sum += __shfl_xor(sum, 32);
      l_q[qt] = l_q[qt] * corr[qt] + sum;
#pragma unroll
      for (int tt = 0; tt < 4; ++tt) {
        pk[qt][tt][0] = cvtpk(p[tt][0], p[tt][1]);
        pk[qt][tt][1] = cvtpk(p[tt][2], p[tt][3]);
      }
    }

    // ---- redistribute P into B-frag layout: lane(lh,l15) gets P[kk2*32+lh*8+j][q]
    bf16x8 pfrag[2][2];
#pragma unroll
    for (int qt = 0; qt < 2; ++qt)
#pragma unroll
      for (int kk2 = 0; kk2 < 2; ++kk2) {
        union { unsigned w[4]; bf16x8 v; } u;
        int ta = 2 * kk2, tb = 2 * kk2 + 1;
        unsigned a, b;
        a = (unsigned)__shfl((int)pk[qt][ta][0], srcA); b = (unsigned)__shfl((int)pk[qt][tb][0], srcA);
        u.w[0] = thi ? b : a;
        a = (unsigned)__shfl((int)pk[qt][ta][1], srcA); b = (unsigned)__shfl((int)pk[qt][tb][1], srcA);
        u.w[1] = thi ? b : a;
        a = (unsigned)__shfl((int)pk[qt][ta][0], srcB); b = (unsigned)__shfl((int)pk[qt][tb][0], srcB);
        u.w[2] = thi ? b : a;
        a = (unsigned)__shfl((int)pk[qt][ta][1], srcB); b = (unsigned)__shfl((int)pk[qt][tb][1], srcB);
        u.w[3] = thi ? b : a;
        pfrag[qt][kk2] = u.v;
      }

    // ---- write prefetched V into other buffer (loads have had QK^T+softmax to land)
    if (pre) writeV(buf ^ 1, vv);

    // ---- rescale O
#pragma unroll
    for (int qt = 0; qt < 2; ++qt)
#pragma unroll
      for (int dt = 0; dt < 8; ++dt)
#pragma unroll
        for (int r = 0; r < 4; ++r) oacc[qt][dt][r] *= corr[qt];

    // ---- PV: A = V^T (direct b128 reads from padded sV), B = pfrag
#pragma unroll
    for (int dt = 0; dt < 8; ++dt) {
#pragma unroll
      for (int kk2 = 0; kk2 < 2; ++kk2) {
        bf16x8 vf = *(const bf16x8*)&sV[buf][dt * 16 + l15][kk2 * 32 + lh * 8];
        oacc[0][dt] = __builtin_amdgcn_mfma_f32_16x16x32_bf16(vf, pfrag[0][kk2], oacc[0][dt], 0, 0, 0);
        oacc[1][dt] = __builtin_amdgcn_mfma_f32_16x16x32_bf16(vf, pfrag[1][kk2], oacc[1][dt], 0, 0, 0);
      }
    }

    asm volatile("s_waitcnt vmcnt(0)" ::: "memory");
    __syncthreads();
    buf ^= 1;
  }

  // ---- epilogue: lane holds O[d=dt*16+lh*4+r][q=qt*16+l15]
#pragma unroll
  for (int qt = 0; qt < 2; ++qt) {
    float inv = 1.0f / l_q[qt];
    size_t row = (size_t)(q0 + qt * 16 + l15) * QD + h * DH;
#pragma unroll
    for (int dt = 0; dt < 8; ++dt) {
      ushort4 o;
      o.x = f2bf(oacc[qt][dt][0] * inv);
      o.y = f2bf(oacc[qt][dt][1] * inv);
      o.z = f2bf(oacc[qt][dt][2] * inv);
      o.w = f2bf(oacc[qt][dt][3] * inv);
      *(ushort4*)(O + row + dt * 16 + lh * 4) = o;
    }
  }
}

// ---------------------------------------------------------------- launcher
extern "C" void kernel_launch(void* const* d_in, const int* in_sizes, int n_in,
                              void* d_out, int out_size, void* d_ws, size_t ws_size,
                              hipStream_t stream)
{
  const float* hs    = (const float*)d_in[0];
  const float* freqs = (const float*)d_in[1];
  const float* Wq    = (const float*)d_in[2];
  const float* Wk    = (const float*)d_in[3];
  const float* Wv    = (const float*)d_in[4];
  const float* Wo    = (const float*)d_in[5];
  const float* qw    = (const float*)d_in[6];
  const float* kw    = (const float*)d_in[7];
  float* out = (float*)d_out;

  char* ws = (char*)d_ws;
  size_t off = 0;
  auto alloc = [&](size_t bytes) {
    char* p = ws + off;
    off += (bytes + 255) & ~(size_t)255;
    return p;
  };
  unsigned short* hs_b   = (unsigned short*)alloc((size_t)S_LEN * HID * 2);
  unsigned short* wqkv_b = (unsigned short*)alloc((size_t)(QD + 2 * KVD) * HID * 2);
  unsigned short* Wo_b   = (unsigned short*)alloc((size_t)HID * QD * 2);
  unsigned short* q_b    = (unsigned short*)alloc((size_t)S_LEN * QD * 2);
  unsigned short* k_b    = (unsigned short*)alloc((size_t)S_LEN * KVD * 2);
  unsigned short* v_b    = (unsigned short*)alloc((size_t)S_LEN * KVD * 2);
  unsigned short* at_b   = (unsigned short*)alloc((size_t)S_LEN * QD * 2);

  auto cast = [&](const float* src, unsigned short* dst, int n) {
    int n4 = n / 4;
    int blocks = (n4 + 255) / 256; if (blocks > 2048) blocks = 2048;
    cast_bf16_k<<<dim3(blocks), dim3(256), 0, stream>>>(src, dst, n4);
  };
  cast(hs, hs_b, S_LEN * HID);
  cast(Wq, wqkv_b,                       QD * HID);
  cast(Wk, wqkv_b + (size_t)QD * HID,    KVD * HID);
  cast(Wv, wqkv_b + (size_t)(QD + KVD) * HID, KVD * HID);
  cast(Wo, Wo_b, HID * QD);

  gemm_qkv<<<dim3((QD + 2 * KVD) / BN, S_LEN / BM), dim3(256), 0, stream>>>(
      hs_b, wqkv_b, freqs, qw, kw, q_b, k_b, v_b);

  attn2_k<<<dim3(S_LEN / 32, NKV), dim3(256), 0, stream>>>(q_b, k_b, v_b, at_b);

  gemm_bt<<<dim3(HID / BN, S_LEN / BM), dim3(256), 0, stream>>>(
      at_b, Wo_b, out, S_LEN, HID, QD);
}

// Round 5
// 501.616 us; speedup vs baseline: 1.4250x; 1.0405x over previous
//
#include <hip/hip_runtime.h>
#include <stdint.h>

#define S_LEN 2048
#define HID   2560
#define NH    32
#define NKV   8
#define DH    128
#define QD    (NH*DH)    // 4096
#define KVD   (NKV*DH)   // 1024

typedef __attribute__((ext_vector_type(8)))  short          bf16x8;
typedef __attribute__((ext_vector_type(4)))  float          f32x4;
typedef __attribute__((ext_vector_type(16))) float          f32x16;
typedef __attribute__((ext_vector_type(8)))  unsigned short us8;

static __device__ __forceinline__ unsigned short f2bf(float f) {
  union { float f; uint32_t u; } v; v.f = f;
  uint32_t u = v.u;
  u += 0x7fff + ((u >> 16) & 1);   // RNE
  return (unsigned short)(u >> 16);
}

static __device__ __forceinline__ void gload16(const void* g, void* l) {
  __builtin_amdgcn_global_load_lds(
      (const __attribute__((address_space(1))) uint32_t*)g,
      (__attribute__((address_space(3))) uint32_t*)l, 16, 0, 0);
}

static __device__ __forceinline__ unsigned cvtpk(float lo, float hi) {
  unsigned r;
  asm volatile("v_cvt_pk_bf16_f32 %0, %1, %2" : "=v"(r) : "v"(lo), "v"(hi));
  return r;
}

// v_permlane32_swap_b32 a, b : a's upper 32 lanes swap with b's lower 32 lanes.
// After: a[i+32] = b_old[i], b[i] = a_old[i+32]; a_lo, b_hi unchanged.
static __device__ __forceinline__ void plswap(unsigned& a, unsigned& b) {
  asm volatile("v_permlane32_swap_b32 %0, %1" : "+v"(a), "+v"(b));
}

// ---------------------------------------------------------------- cast f32->bf16
__global__ void cast_bf16_k(const float* __restrict__ in,
                            unsigned short* __restrict__ out, int n4) {
  int stride = gridDim.x * blockDim.x;
  for (int i = blockIdx.x * blockDim.x + threadIdx.x; i < n4; i += stride) {
    float4 v = ((const float4*)in)[i];
    ushort4 o;
    o.x = f2bf(v.x); o.y = f2bf(v.y); o.z = f2bf(v.z); o.w = f2bf(v.w);
    ((ushort4*)out)[i] = o;
  }
}

// ---------------------------------------------------------------- GEMM  C = A * B^T (f32 out)
#define BM 128
#define BN 128
#define BK 32

__global__ __launch_bounds__(256)
void gemm_bt(const unsigned short* __restrict__ A,
             const unsigned short* __restrict__ B,
             float* __restrict__ Cf, int M, int N, int K)
{
  __shared__ __align__(16) unsigned short sA[BM * BK];
  __shared__ __align__(16) unsigned short sB[BN * BK];
  const int tid  = threadIdx.x;
  const int wave = tid >> 6, lane = tid & 63;
  const int wr   = wave >> 1, wc = wave & 1;
  const int brow = blockIdx.y, bcol = blockIdx.x;
  const int l15  = lane & 15, lh = lane >> 4;

  f32x4 acc[4][4] = {};

  for (int k0 = 0; k0 < K; k0 += BK) {
    __syncthreads();
#pragma unroll
    for (int c = 0; c < 2; ++c) {
      int chunk = wave * 2 + c;
      int f = chunk * 512 + lane * 8;
      int row = f >> 5, col = f & 31;
      gload16(A + (size_t)(brow * BM + row) * K + k0 + col, (char*)sA + chunk * 1024);
      gload16(B + (size_t)(bcol * BN + row) * K + k0 + col, (char*)sB + chunk * 1024);
    }
    __syncthreads();

    bf16x8 af[4], bfr[4];
#pragma unroll
    for (int i = 0; i < 4; ++i)
      af[i] = *(const bf16x8*)((const char*)sA + (wr * 64 + i * 16 + l15) * 64 + lh * 16);
#pragma unroll
    for (int j = 0; j < 4; ++j)
      bfr[j] = *(const bf16x8*)((const char*)sB + (wc * 64 + j * 16 + l15) * 64 + lh * 16);
#pragma unroll
    for (int i = 0; i < 4; ++i)
#pragma unroll
      for (int j = 0; j < 4; ++j)
        acc[i][j] = __builtin_amdgcn_mfma_f32_16x16x32_bf16(af[i], bfr[j], acc[i][j], 0, 0, 0);
  }

#pragma unroll
  for (int i = 0; i < 4; ++i)
#pragma unroll
    for (int j = 0; j < 4; ++j) {
      int row = brow * BM + wr * 64 + i * 16 + lh * 4;
      int col = bcol * BN + wc * 64 + j * 16 + l15;
#pragma unroll
      for (int r = 0; r < 4; ++r)
        Cf[(size_t)(row + r) * N + col] = acc[i][j][r];
    }
}

// ---------------------------------------------------------------- fused QKV GEMM + RMSNorm + RoPE
__global__ __launch_bounds__(256)
void gemm_qkv(const unsigned short* __restrict__ A,
              const unsigned short* __restrict__ B,
              const float* __restrict__ freqs,
              const float* __restrict__ qw, const float* __restrict__ kw,
              unsigned short* __restrict__ Qo,
              unsigned short* __restrict__ Ko,
              unsigned short* __restrict__ Vo)
{
  __shared__ __align__(16) unsigned short sA[BM * BK];
  __shared__ __align__(16) unsigned short sB[BN * BK];
  const int tid  = threadIdx.x;
  const int wave = tid >> 6, lane = tid & 63;
  const int brow = blockIdx.y, bcol = blockIdx.x;
  const int l15  = lane & 15, lh = lane >> 4;

  f32x4 acc[2][8] = {};

  for (int k0 = 0; k0 < HID; k0 += BK) {
    __syncthreads();
#pragma unroll
    for (int c = 0; c < 2; ++c) {
      int chunk = wave * 2 + c;
      int f = chunk * 512 + lane * 8;
      int row = f >> 5, col = f & 31;
      gload16(A + (size_t)(brow * BM + row) * HID + k0 + col, (char*)sA + chunk * 1024);
      gload16(B + (size_t)(bcol * BN + row) * HID + k0 + col, (char*)sB + chunk * 1024);
    }
    __syncthreads();

    bf16x8 af[2], bfr[8];
#pragma unroll
    for (int i = 0; i < 2; ++i)
      af[i] = *(const bf16x8*)((const char*)sA + (wave * 32 + i * 16 + l15) * 64 + lh * 16);
#pragma unroll
    for (int j = 0; j < 8; ++j)
      bfr[j] = *(const bf16x8*)((const char*)sB + (j * 16 + l15) * 64 + lh * 16);
#pragma unroll
    for (int i = 0; i < 2; ++i)
#pragma unroll
      for (int j = 0; j < 8; ++j)
        acc[i][j] = __builtin_amdgcn_mfma_f32_16x16x32_bf16(af[i], bfr[j], acc[i][j], 0, 0, 0);
  }

  const int ncol0  = bcol * BN;
  const int region = (ncol0 < QD) ? 0 : (ncol0 < QD + KVD ? 1 : 2);
  const float* nw  = (region == 0) ? qw : kw;

#pragma unroll
  for (int i = 0; i < 2; ++i) {
#pragma unroll
    for (int r = 0; r < 4; ++r) {
      int s = brow * BM + wave * 32 + i * 16 + lh * 4 + r;
      float v[8];
#pragma unroll
      for (int j = 0; j < 8; ++j) v[j] = acc[i][j][r];
      if (region < 2) {
        float ss = 0.f;
#pragma unroll
        for (int j = 0; j < 8; ++j) ss += v[j] * v[j];
        ss += __shfl_xor(ss, 1); ss += __shfl_xor(ss, 2);
        ss += __shfl_xor(ss, 4); ss += __shfl_xor(ss, 8);
        float rsq = rsqrtf(ss * (1.0f / 128.0f) + 1e-6f);
        float y[8];
#pragma unroll
        for (int j = 0; j < 8; ++j) y[j] = v[j] * rsq * nw[j * 16 + l15];
        const float* cr = freqs + (size_t)s * DH;
        const float* sr = freqs + (size_t)(S_LEN + s) * DH;
#pragma unroll
        for (int j = 0; j < 4; ++j) {
          int d1 = j * 16 + l15, d2 = (j + 4) * 16 + l15;
          v[j]     = y[j]     * cr[d1] - y[j + 4] * sr[d1];
          v[j + 4] = y[j + 4] * cr[d2] + y[j]     * sr[d2];
        }
      }
      unsigned short* dst;
      if (region == 0)      dst = Qo + (size_t)s * QD  + ncol0;
      else if (region == 1) dst = Ko + (size_t)s * KVD + (ncol0 - QD);
      else                  dst = Vo + (size_t)s * KVD + (ncol0 - QD - KVD);
#pragma unroll
      for (int j = 0; j < 8; ++j) dst[j * 16 + l15] = f2bf(v[j]);
    }
  }
}

// ---------------------------------------------------------------- flash attention, 32x32 MFMA (m214 structure)
// grid (S/32, NKV). block 256 = 4 waves; wave w = head kvh*4+w, 32 q-rows (one 32-col MFMA tile).
// Swapped QK^T: S^T C-tile has col=lane&31=q, row k=(reg&3)+8*(reg>>2)+4*(lane>>5).
// Softmax fully lane-local (+1 shfl_xor(32)); P->B-frag via cvt_pk + permlane32_swap (no DS).
// sK: XOR-swizzled row-major [64][128]; sV: padded transpose [d][kv] [128][72].
__global__ __launch_bounds__(256, 2)
void attn2_k(const unsigned short* __restrict__ Q,
             const unsigned short* __restrict__ Kb,
             const unsigned short* __restrict__ Vb,
             unsigned short* __restrict__ O)
{
  const float SC = 0.08838834764831845f * 1.4426950408889634f;  // 1/sqrt(128) * log2(e)
  __shared__ __align__(16) unsigned short sK[2][64 * 128];
  __shared__ __align__(16) unsigned short sV[2][128][72];

  const int kvh  = blockIdx.y;
  const int q0   = blockIdx.x * 32;
  const int wave = threadIdx.x >> 6, lane = threadIdx.x & 63;
  const int l31  = lane & 31, half = lane >> 5;
  const int h    = kvh * 4 + wave;
  const int vc0  = wave * 32;

  // Q fragments as B-operand: col=l31=q-row, k'(=d) = ds*16 + half*8 + j
  bf16x8 qf[8];
  {
    const unsigned short* qp = Q + (size_t)(q0 + l31) * QD + h * DH + half * 8;
#pragma unroll
    for (int ds = 0; ds < 8; ++ds) qf[ds] = *(const bf16x8*)(qp + ds * 16);
  }

  f32x16 oacc[4] = {};
  float m_c = -1e30f, l_c = 0.f;

  auto stageK = [&](int b, int t0) {
#pragma unroll
    for (int c = 0; c < 4; ++c) {
      int chunk = wave * 4 + c;
      int fb = chunk * 1024 + lane * 16;
      int row = fb >> 8;
      int gi = (fb & 255) ^ ((row & 7) << 4);
      gload16(Kb + (size_t)(t0 + row) * KVD + kvh * DH + (gi >> 1),
              (char*)sK[b] + chunk * 1024);
    }
  };
  auto loadV = [&](us8* vv, int t0) {
    const unsigned short* vsrc = Vb + (size_t)(t0 + lane) * KVD + kvh * DH + vc0;
#pragma unroll
    for (int u = 0; u < 4; ++u) vv[u] = *(const us8*)(vsrc + u * 8);
  };
  auto writeV = [&](int b, const us8* vv) {
#pragma unroll
    for (int u = 0; u < 4; ++u)
#pragma unroll
      for (int k = 0; k < 8; ++k)
        sV[b][vc0 + u * 8 + k][lane] = (unsigned short)vv[u][k];
  };

  {
    us8 vv[4];
    stageK(0, 0);
    loadV(vv, 0);
    writeV(0, vv);
  }
  asm volatile("s_waitcnt vmcnt(0)" ::: "memory");
  __syncthreads();
  int buf = 0;

  for (int t = 0; t < S_LEN / 64; ++t) {
    const bool pre = (t + 1 < S_LEN / 64);
    us8 vv[4];
    if (pre) { stageK(buf ^ 1, (t + 1) * 64); loadV(vv, (t + 1) * 64); }

    // ---- QK^T swapped (A=K, B=Q): sm[kc] C-tile = S^T[k=kc*32+..][q]
    f32x16 sm[2] = {};
    __builtin_amdgcn_s_setprio(1);
#pragma unroll
    for (int kc = 0; kc < 2; ++kc) {
      int krow = kc * 32 + l31;
      int rb = krow * 256, sw = (krow & 7) << 4;
#pragma unroll
      for (int ds = 0; ds < 8; ++ds) {
        bf16x8 kf = *(const bf16x8*)((const char*)sK[buf] + rb + ((ds * 32 + half * 16) ^ sw));
        sm[kc] = __builtin_amdgcn_mfma_f32_32x32x16_bf16(kf, qf[ds], sm[kc], 0, 0, 0);
      }
    }
    __builtin_amdgcn_s_setprio(0);

    // ---- online softmax: lane owns q=l31; k split with lane^32 partner
    float mraw = sm[0][0];
#pragma unroll
    for (int kc = 0; kc < 2; ++kc)
#pragma unroll
      for (int r = 0; r < 16; ++r) mraw = fmaxf(mraw, sm[kc][r]);
    mraw = fmaxf(mraw, __shfl_xor(mraw, 32));
    float mn = fmaxf(m_c, mraw * SC);
    float corr = exp2f(m_c - mn);
    m_c = mn;

    float p[2][16];
    float sum = 0.f;
#pragma unroll
    for (int kc = 0; kc < 2; ++kc)
#pragma unroll
      for (int r = 0; r < 16; ++r) {
        p[kc][r] = exp2f(sm[kc][r] * SC - mn);
        sum += p[kc][r];
      }
    sum += __shfl_xor(sum, 32);
    l_c = l_c * corr + sum;

    // ---- P -> B-frag via cvt_pk + permlane32_swap (k' = ks*16 + half*8 + j)
    bf16x8 pfrag[4];
#pragma unroll
    for (int kc = 0; kc < 2; ++kc)
#pragma unroll
      for (int ksl = 0; ksl < 2; ++ksl) {
        int rb = ksl * 8;
        unsigned x0 = cvtpk(p[kc][rb + 0], p[kc][rb + 1]);
        unsigned y0 = cvtpk(p[kc][rb + 4], p[kc][rb + 5]);
        unsigned x1 = cvtpk(p[kc][rb + 2], p[kc][rb + 3]);
        unsigned y1 = cvtpk(p[kc][rb + 6], p[kc][rb + 7]);
        plswap(x0, y0);   // x0 -> word0, y0 -> word2
        plswap(x1, y1);   // x1 -> word1, y1 -> word3
        union { unsigned w[4]; bf16x8 v; } u;
        u.w[0] = x0; u.w[1] = x1; u.w[2] = y0; u.w[3] = y1;
        pfrag[kc * 2 + ksl] = u.v;
      }

    // ---- write prefetched V into other buffer
    if (pre) writeV(buf ^ 1, vv);

    // ---- rescale O
#pragma unroll
    for (int dt = 0; dt < 4; ++dt)
#pragma unroll
      for (int r = 0; r < 16; ++r) oacc[dt][r] *= corr;

    // ---- PV: A = V^T (b128 from padded sV), B = pfrag
    __builtin_amdgcn_s_setprio(1);
#pragma unroll
    for (int dt = 0; dt < 4; ++dt) {
#pragma unroll
      for (int ks = 0; ks < 4; ++ks) {
        bf16x8 vfa = *(const bf16x8*)&sV[buf][dt * 32 + l31][ks * 16 + half * 8];
        oacc[dt] = __builtin_amdgcn_mfma_f32_32x32x16_bf16(vfa, pfrag[ks], oacc[dt], 0, 0, 0);
      }
    }
    __builtin_amdgcn_s_setprio(0);

    asm volatile("s_waitcnt vmcnt(0)" ::: "memory");
    __syncthreads();
    buf ^= 1;
  }

  // ---- epilogue: lane holds O[d = dt*32 + (r&3)+8*(r>>2)+4*half][q=l31]
  {
    float inv = 1.0f / l_c;
    unsigned short* orow = O + (size_t)(q0 + l31) * QD + h * DH;
#pragma unroll
    for (int dt = 0; dt < 4; ++dt)
#pragma unroll
      for (int r = 0; r < 16; r += 2) {
        int d = dt * 32 + (r & 3) + 8 * (r >> 2) + 4 * half;
        unsigned w = cvtpk(oacc[dt][r] * inv, oacc[dt][r + 1] * inv);
        *(unsigned*)(orow + d) = w;
      }
  }
}

// ---------------------------------------------------------------- launcher
extern "C" void kernel_launch(void* const* d_in, const int* in_sizes, int n_in,
                              void* d_out, int out_size, void* d_ws, size_t ws_size,
                              hipStream_t stream)
{
  const float* hs    = (const float*)d_in[0];
  const float* freqs = (const float*)d_in[1];
  const float* Wq    = (const float*)d_in[2];
  const float* Wk    = (const float*)d_in[3];
  const float* Wv    = (const float*)d_in[4];
  const float* Wo    = (const float*)d_in[5];
  const float* qw    = (const float*)d_in[6];
  const float* kw    = (const float*)d_in[7];
  float* out = (float*)d_out;

  char* ws = (char*)d_ws;
  size_t off = 0;
  auto alloc = [&](size_t bytes) {
    char* p = ws + off;
    off += (bytes + 255) & ~(size_t)255;
    return p;
  };
  unsigned short* hs_b   = (unsigned short*)alloc((size_t)S_LEN * HID * 2);
  unsigned short* wqkv_b = (unsigned short*)alloc((size_t)(QD + 2 * KVD) * HID * 2);
  unsigned short* Wo_b   = (unsigned short*)alloc((size_t)HID * QD * 2);
  unsigned short* q_b    = (unsigned short*)alloc((size_t)S_LEN * QD * 2);
  unsigned short* k_b    = (unsigned short*)alloc((size_t)S_LEN * KVD * 2);
  unsigned short* v_b    = (unsigned short*)alloc((size_t)S_LEN * KVD * 2);
  unsigned short* at_b   = (unsigned short*)alloc((size_t)S_LEN * QD * 2);

  auto cast = [&](const float* src, unsigned short* dst, int n) {
    int n4 = n / 4;
    int blocks = (n4 + 255) / 256; if (blocks > 2048) blocks = 2048;
    cast_bf16_k<<<dim3(blocks), dim3(256), 0, stream>>>(src, dst, n4);
  };
  cast(hs, hs_b, S_LEN * HID);
  cast(Wq, wqkv_b,                       QD * HID);
  cast(Wk, wqkv_b + (size_t)QD * HID,    KVD * HID);
  cast(Wv, wqkv_b + (size_t)(QD + KVD) * HID, KVD * HID);
  cast(Wo, Wo_b, HID * QD);

  gemm_qkv<<<dim3((QD + 2 * KVD) / BN, S_LEN / BM), dim3(256), 0, stream>>>(
      hs_b, wqkv_b, freqs, qw, kw, q_b, k_b, v_b);

  attn2_k<<<dim3(S_LEN / 32, NKV), dim3(256), 0, stream>>>(q_b, k_b, v_b, at_b);

  gemm_bt<<<dim3(HID / BN, S_LEN / BM), dim3(256), 0, stream>>>(
      at_b, Wo_b, out, S_LEN, HID, QD);
}

// Round 6
// 458.117 us; speedup vs baseline: 1.5604x; 1.0950x over previous
//
#include <hip/hip_runtime.h>
#include <stdint.h>

#define S_LEN 2048
#define HID   2560
#define NH    32
#define NKV   8
#define DH    128
#define QD    (NH*DH)    // 4096
#define KVD   (NKV*DH)   // 1024

typedef __attribute__((ext_vector_type(8)))  short          bf16x8;
typedef __attribute__((ext_vector_type(4)))  float          f32x4;
typedef __attribute__((ext_vector_type(16))) float          f32x16;
typedef __attribute__((ext_vector_type(8)))  unsigned short us8;

static __device__ __forceinline__ unsigned short f2bf(float f) {
  union { float f; uint32_t u; } v; v.f = f;
  uint32_t u = v.u;
  u += 0x7fff + ((u >> 16) & 1);   // RNE
  return (unsigned short)(u >> 16);
}

static __device__ __forceinline__ void gload16(const void* g, void* l) {
  __builtin_amdgcn_global_load_lds(
      (const __attribute__((address_space(1))) uint32_t*)g,
      (__attribute__((address_space(3))) uint32_t*)l, 16, 0, 0);
}

static __device__ __forceinline__ unsigned cvtpk(float lo, float hi) {
  unsigned r;
  asm volatile("v_cvt_pk_bf16_f32 %0, %1, %2" : "=v"(r) : "v"(lo), "v"(hi));
  return r;
}

// v_permlane32_swap_b32 a, b : a's upper 32 lanes swap with b's lower 32 lanes.
static __device__ __forceinline__ void plswap(unsigned& a, unsigned& b) {
  asm volatile("v_permlane32_swap_b32 %0, %1" : "+v"(a), "+v"(b));
}

// ---------------------------------------------------------------- fused cast f32->bf16 (all 5 arrays, contiguous dst)
#define N_HS4 1310720                 // 2048*2560/4
#define B0 1310720                    // end hs
#define B1 3932160                    // end Wq (+4096*2560/4)
#define B2 4587520                    // end Wk (+1024*2560/4)
#define B3 5242880                    // end Wv
#define B4 7864320                    // end Wo (+2560*4096/4)

__global__ void cast_all_k(const float* __restrict__ hs,
                           const float* __restrict__ Wq,
                           const float* __restrict__ Wk,
                           const float* __restrict__ Wv,
                           const float* __restrict__ Wo,
                           ushort4* __restrict__ dst) {
  int stride = gridDim.x * blockDim.x;
  for (int i = blockIdx.x * blockDim.x + threadIdx.x; i < B4; i += stride) {
    const float* s; int rel;
    if (i < B0)      { s = hs; rel = i; }
    else if (i < B1) { s = Wq; rel = i - B0; }
    else if (i < B2) { s = Wk; rel = i - B1; }
    else if (i < B3) { s = Wv; rel = i - B2; }
    else             { s = Wo; rel = i - B3; }
    float4 v = ((const float4*)s)[rel];
    ushort4 o;
    o.x = f2bf(v.x); o.y = f2bf(v.y); o.z = f2bf(v.z); o.w = f2bf(v.w);
    dst[i] = o;
  }
}

// ---------------------------------------------------------------- GEMM  C = A * B^T (f32 out)
// BK=64, XOR-swizzled LDS (byte ^ ((row&7)<<4), pre-swizzled global source),
// XCD-contiguous block swizzle (grid must be %8==0 blocks).
#define BM 128
#define BN 128
#define BK 64

__global__ __launch_bounds__(256)
void gemm_bt(const unsigned short* __restrict__ A,
             const unsigned short* __restrict__ B,
             float* __restrict__ Cf, int M, int N, int K)
{
  __shared__ __align__(16) unsigned short sA[BM * BK];
  __shared__ __align__(16) unsigned short sB[BN * BK];
  const int tid  = threadIdx.x;
  const int wave = tid >> 6, lane = tid & 63;
  const int wr   = wave >> 1, wc = wave & 1;
  const int l15  = lane & 15, lh = lane >> 4;

  // T1: XCD-contiguous remap of linearized block id
  const int nwg = gridDim.x * gridDim.y;
  const int wg  = blockIdx.y * gridDim.x + blockIdx.x;
  const int swz = (wg & 7) * (nwg >> 3) + (wg >> 3);
  const int bcol = swz % gridDim.x, brow = swz / gridDim.x;

  f32x4 acc[4][4] = {};

  for (int k0 = 0; k0 < K; k0 += BK) {
    __syncthreads();
#pragma unroll
    for (int c = 0; c < 4; ++c) {
      int fb  = (wave * 4 + c) * 1024;
      int db  = fb + lane * 16;            // dest byte (HW adds lane*16 to base)
      int row = db >> 7;
      int gi  = (db & 127) ^ ((row & 7) << 4);
      gload16(A + (size_t)(brow * BM + row) * K + k0 + (gi >> 1), (char*)sA + fb);
      gload16(B + (size_t)(bcol * BN + row) * K + k0 + (gi >> 1), (char*)sB + fb);
    }
    __syncthreads();

#pragma unroll
    for (int ks = 0; ks < 2; ++ks) {
      bf16x8 af[4], bfr[4];
#pragma unroll
      for (int i = 0; i < 4; ++i) {
        int row = wr * 64 + i * 16 + l15;
        af[i] = *(const bf16x8*)((const char*)sA + row * 128 +
                                 ((ks * 64 + lh * 16) ^ ((row & 7) << 4)));
      }
#pragma unroll
      for (int j = 0; j < 4; ++j) {
        int row = wc * 64 + j * 16 + l15;
        bfr[j] = *(const bf16x8*)((const char*)sB + row * 128 +
                                  ((ks * 64 + lh * 16) ^ ((row & 7) << 4)));
      }
#pragma unroll
      for (int i = 0; i < 4; ++i)
#pragma unroll
        for (int j = 0; j < 4; ++j)
          acc[i][j] = __builtin_amdgcn_mfma_f32_16x16x32_bf16(af[i], bfr[j], acc[i][j], 0, 0, 0);
    }
  }

#pragma unroll
  for (int i = 0; i < 4; ++i)
#pragma unroll
    for (int j = 0; j < 4; ++j) {
      int row = brow * BM + wr * 64 + i * 16 + lh * 4;
      int col = bcol * BN + wc * 64 + j * 16 + l15;
#pragma unroll
      for (int r = 0; r < 4; ++r)
        Cf[(size_t)(row + r) * N + col] = acc[i][j][r];
    }
}

// ---------------------------------------------------------------- fused QKV GEMM + RMSNorm + RoPE
__global__ __launch_bounds__(256)
void gemm_qkv(const unsigned short* __restrict__ A,
              const unsigned short* __restrict__ B,
              const float* __restrict__ freqs,
              const float* __restrict__ qw, const float* __restrict__ kw,
              unsigned short* __restrict__ Qo,
              unsigned short* __restrict__ Ko,
              unsigned short* __restrict__ Vo)
{
  __shared__ __align__(16) unsigned short sA[BM * BK];
  __shared__ __align__(16) unsigned short sB[BN * BK];
  const int tid  = threadIdx.x;
  const int wave = tid >> 6, lane = tid & 63;
  const int l15  = lane & 15, lh = lane >> 4;

  const int nwg = gridDim.x * gridDim.y;
  const int wg  = blockIdx.y * gridDim.x + blockIdx.x;
  const int swz = (wg & 7) * (nwg >> 3) + (wg >> 3);
  const int bcol = swz % gridDim.x, brow = swz / gridDim.x;

  f32x4 acc[2][8] = {};

  for (int k0 = 0; k0 < HID; k0 += BK) {
    __syncthreads();
#pragma unroll
    for (int c = 0; c < 4; ++c) {
      int fb  = (wave * 4 + c) * 1024;
      int db  = fb + lane * 16;
      int row = db >> 7;
      int gi  = (db & 127) ^ ((row & 7) << 4);
      gload16(A + (size_t)(brow * BM + row) * HID + k0 + (gi >> 1), (char*)sA + fb);
      gload16(B + (size_t)(bcol * BN + row) * HID + k0 + (gi >> 1), (char*)sB + fb);
    }
    __syncthreads();

#pragma unroll
    for (int ks = 0; ks < 2; ++ks) {
      bf16x8 af[2], bfr[8];
#pragma unroll
      for (int i = 0; i < 2; ++i) {
        int row = wave * 32 + i * 16 + l15;
        af[i] = *(const bf16x8*)((const char*)sA + row * 128 +
                                 ((ks * 64 + lh * 16) ^ ((row & 7) << 4)));
      }
#pragma unroll
      for (int j = 0; j < 8; ++j) {
        int row = j * 16 + l15;
        bfr[j] = *(const bf16x8*)((const char*)sB + row * 128 +
                                  ((ks * 64 + lh * 16) ^ ((row & 7) << 4)));
      }
#pragma unroll
      for (int i = 0; i < 2; ++i)
#pragma unroll
        for (int j = 0; j < 8; ++j)
          acc[i][j] = __builtin_amdgcn_mfma_f32_16x16x32_bf16(af[i], bfr[j], acc[i][j], 0, 0, 0);
    }
  }

  const int ncol0  = bcol * BN;
  const int region = (ncol0 < QD) ? 0 : (ncol0 < QD + KVD ? 1 : 2);
  const float* nw  = (region == 0) ? qw : kw;

#pragma unroll
  for (int i = 0; i < 2; ++i) {
#pragma unroll
    for (int r = 0; r < 4; ++r) {
      int s = brow * BM + wave * 32 + i * 16 + lh * 4 + r;
      float v[8];
#pragma unroll
      for (int j = 0; j < 8; ++j) v[j] = acc[i][j][r];
      if (region < 2) {
        float ss = 0.f;
#pragma unroll
        for (int j = 0; j < 8; ++j) ss += v[j] * v[j];
        ss += __shfl_xor(ss, 1); ss += __shfl_xor(ss, 2);
        ss += __shfl_xor(ss, 4); ss += __shfl_xor(ss, 8);
        float rsq = rsqrtf(ss * (1.0f / 128.0f) + 1e-6f);
        float y[8];
#pragma unroll
        for (int j = 0; j < 8; ++j) y[j] = v[j] * rsq * nw[j * 16 + l15];
        const float* cr = freqs + (size_t)s * DH;
        const float* sr = freqs + (size_t)(S_LEN + s) * DH;
#pragma unroll
        for (int j = 0; j < 4; ++j) {
          int d1 = j * 16 + l15, d2 = (j + 4) * 16 + l15;
          v[j]     = y[j]     * cr[d1] - y[j + 4] * sr[d1];
          v[j + 4] = y[j + 4] * cr[d2] + y[j]     * sr[d2];
        }
      }
      unsigned short* dst;
      if (region == 0)      dst = Qo + (size_t)s * QD  + ncol0;
      else if (region == 1) dst = Ko + (size_t)s * KVD + (ncol0 - QD);
      else                  dst = Vo + (size_t)s * KVD + (ncol0 - QD - KVD);
#pragma unroll
      for (int j = 0; j < 8; ++j) dst[j * 16 + l15] = f2bf(v[j]);
    }
  }
}

// ---------------------------------------------------------------- flash attention, 32x32 MFMA (unchanged from round 5)
__global__ __launch_bounds__(256, 2)
void attn2_k(const unsigned short* __restrict__ Q,
             const unsigned short* __restrict__ Kb,
             const unsigned short* __restrict__ Vb,
             unsigned short* __restrict__ O)
{
  const float SC = 0.08838834764831845f * 1.4426950408889634f;  // 1/sqrt(128) * log2(e)
  __shared__ __align__(16) unsigned short sK[2][64 * 128];
  __shared__ __align__(16) unsigned short sV[2][128][72];

  const int kvh  = blockIdx.y;
  const int q0   = blockIdx.x * 32;
  const int wave = threadIdx.x >> 6, lane = threadIdx.x & 63;
  const int l31  = lane & 31, half = lane >> 5;
  const int h    = kvh * 4 + wave;
  const int vc0  = wave * 32;

  bf16x8 qf[8];
  {
    const unsigned short* qp = Q + (size_t)(q0 + l31) * QD + h * DH + half * 8;
#pragma unroll
    for (int ds = 0; ds < 8; ++ds) qf[ds] = *(const bf16x8*)(qp + ds * 16);
  }

  f32x16 oacc[4] = {};
  float m_c = -1e30f, l_c = 0.f;

  auto stageK = [&](int b, int t0) {
#pragma unroll
    for (int c = 0; c < 4; ++c) {
      int chunk = wave * 4 + c;
      int fb = chunk * 1024 + lane * 16;
      int row = fb >> 8;
      int gi = (fb & 255) ^ ((row & 7) << 4);
      gload16(Kb + (size_t)(t0 + row) * KVD + kvh * DH + (gi >> 1),
              (char*)sK[b] + chunk * 1024);
    }
  };
  auto loadV = [&](us8* vv, int t0) {
    const unsigned short* vsrc = Vb + (size_t)(t0 + lane) * KVD + kvh * DH + vc0;
#pragma unroll
    for (int u = 0; u < 4; ++u) vv[u] = *(const us8*)(vsrc + u * 8);
  };
  auto writeV = [&](int b, const us8* vv) {
#pragma unroll
    for (int u = 0; u < 4; ++u)
#pragma unroll
      for (int k = 0; k < 8; ++k)
        sV[b][vc0 + u * 8 + k][lane] = (unsigned short)vv[u][k];
  };

  {
    us8 vv[4];
    stageK(0, 0);
    loadV(vv, 0);
    writeV(0, vv);
  }
  asm volatile("s_waitcnt vmcnt(0)" ::: "memory");
  __syncthreads();
  int buf = 0;

  for (int t = 0; t < S_LEN / 64; ++t) {
    const bool pre = (t + 1 < S_LEN / 64);
    us8 vv[4];
    if (pre) { stageK(buf ^ 1, (t + 1) * 64); loadV(vv, (t + 1) * 64); }

    f32x16 sm[2] = {};
    __builtin_amdgcn_s_setprio(1);
#pragma unroll
    for (int kc = 0; kc < 2; ++kc) {
      int krow = kc * 32 + l31;
      int rb = krow * 256, sw = (krow & 7) << 4;
#pragma unroll
      for (int ds = 0; ds < 8; ++ds) {
        bf16x8 kf = *(const bf16x8*)((const char*)sK[buf] + rb + ((ds * 32 + half * 16) ^ sw));
        sm[kc] = __builtin_amdgcn_mfma_f32_32x32x16_bf16(kf, qf[ds], sm[kc], 0, 0, 0);
      }
    }
    __builtin_amdgcn_s_setprio(0);

    float mraw = sm[0][0];
#pragma unroll
    for (int kc = 0; kc < 2; ++kc)
#pragma unroll
      for (int r = 0; r < 16; ++r) mraw = fmaxf(mraw, sm[kc][r]);
    mraw = fmaxf(mraw, __shfl_xor(mraw, 32));
    float mn = fmaxf(m_c, mraw * SC);
    float corr = exp2f(m_c - mn);
    m_c = mn;

    float p[2][16];
    float sum = 0.f;
#pragma unroll
    for (int kc = 0; kc < 2; ++kc)
#pragma unroll
      for (int r = 0; r < 16; ++r) {
        p[kc][r] = exp2f(sm[kc][r] * SC - mn);
        sum += p[kc][r];
      }
    sum += __shfl_xor(sum, 32);
    l_c = l_c * corr + sum;

    bf16x8 pfrag[4];
#pragma unroll
    for (int kc = 0; kc < 2; ++kc)
#pragma unroll
      for (int ksl = 0; ksl < 2; ++ksl) {
        int rb = ksl * 8;
        unsigned x0 = cvtpk(p[kc][rb + 0], p[kc][rb + 1]);
        unsigned y0 = cvtpk(p[kc][rb + 4], p[kc][rb + 5]);
        unsigned x1 = cvtpk(p[kc][rb + 2], p[kc][rb + 3]);
        unsigned y1 = cvtpk(p[kc][rb + 6], p[kc][rb + 7]);
        plswap(x0, y0);
        plswap(x1, y1);
        union { unsigned w[4]; bf16x8 v; } u;
        u.w[0] = x0; u.w[1] = x1; u.w[2] = y0; u.w[3] = y1;
        pfrag[kc * 2 + ksl] = u.v;
      }

    if (pre) writeV(buf ^ 1, vv);

#pragma unroll
    for (int dt = 0; dt < 4; ++dt)
#pragma unroll
      for (int r = 0; r < 16; ++r) oacc[dt][r] *= corr;

    __builtin_amdgcn_s_setprio(1);
#pragma unroll
    for (int dt = 0; dt < 4; ++dt) {
#pragma unroll
      for (int ks = 0; ks < 4; ++ks) {
        bf16x8 vfa = *(const bf16x8*)&sV[buf][dt * 32 + l31][ks * 16 + half * 8];
        oacc[dt] = __builtin_amdgcn_mfma_f32_32x32x16_bf16(vfa, pfrag[ks], oacc[dt], 0, 0, 0);
      }
    }
    __builtin_amdgcn_s_setprio(0);

    asm volatile("s_waitcnt vmcnt(0)" ::: "memory");
    __syncthreads();
    buf ^= 1;
  }

  {
    float inv = 1.0f / l_c;
    unsigned short* orow = O + (size_t)(q0 + l31) * QD + h * DH;
#pragma unroll
    for (int dt = 0; dt < 4; ++dt)
#pragma unroll
      for (int r = 0; r < 16; r += 2) {
        int d = dt * 32 + (r & 3) + 8 * (r >> 2) + 4 * half;
        unsigned w = cvtpk(oacc[dt][r] * inv, oacc[dt][r + 1] * inv);
        *(unsigned*)(orow + d) = w;
      }
  }
}

// ---------------------------------------------------------------- launcher
extern "C" void kernel_launch(void* const* d_in, const int* in_sizes, int n_in,
                              void* d_out, int out_size, void* d_ws, size_t ws_size,
                              hipStream_t stream)
{
  const float* hs    = (const float*)d_in[0];
  const float* freqs = (const float*)d_in[1];
  const float* Wq    = (const float*)d_in[2];
  const float* Wk    = (const float*)d_in[3];
  const float* Wv    = (const float*)d_in[4];
  const float* Wo    = (const float*)d_in[5];
  const float* qw    = (const float*)d_in[6];
  const float* kw    = (const float*)d_in[7];
  float* out = (float*)d_out;

  char* ws = (char*)d_ws;
  size_t off = 0;
  auto alloc = [&](size_t bytes) {
    char* p = ws + off;
    off += (bytes + 255) & ~(size_t)255;
    return p;
  };
  unsigned short* hs_b   = (unsigned short*)alloc((size_t)S_LEN * HID * 2);
  unsigned short* wqkv_b = (unsigned short*)alloc((size_t)(QD + 2 * KVD) * HID * 2);
  unsigned short* Wo_b   = (unsigned short*)alloc((size_t)HID * QD * 2);
  unsigned short* q_b    = (unsigned short*)alloc((size_t)S_LEN * QD * 2);
  unsigned short* k_b    = (unsigned short*)alloc((size_t)S_LEN * KVD * 2);
  unsigned short* v_b    = (unsigned short*)alloc((size_t)S_LEN * KVD * 2);
  unsigned short* at_b   = (unsigned short*)alloc((size_t)S_LEN * QD * 2);

  // hs_b / wqkv_b / Wo_b are contiguous (all sizes 256-aligned): one fused cast.
  cast_all_k<<<dim3(4096), dim3(256), 0, stream>>>(hs, Wq, Wk, Wv, Wo, (ushort4*)hs_b);

  gemm_qkv<<<dim3((QD + 2 * KVD) / BN, S_LEN / BM), dim3(256), 0, stream>>>(
      hs_b, wqkv_b, freqs, qw, kw, q_b, k_b, v_b);

  attn2_k<<<dim3(S_LEN / 32, NKV), dim3(256), 0, stream>>>(q_b, k_b, v_b, at_b);

  gemm_bt<<<dim3(HID / BN, S_LEN / BM), dim3(256), 0, stream>>>(
      at_b, Wo_b, out, S_LEN, HID, QD);
}